// Round 2
// baseline (438.020 us; speedup 1.0000x reference)
//
#include <hip/hip_runtime.h>

#define T_SEQ 512
#define HID   50
#define NB    8           // batch rows per block (MFMA N=16: cols 0-7 = L0 batch, 8-15 = L1 batch)
#define BLK   832         // 13 waves; wave w owns L0 Mtile w AND L1 Mtile w

typedef float v4f  __attribute__((ext_vector_type(4)));
typedef _Float16 f16;
typedef f16  f16x8 __attribute__((ext_vector_type(8)));
typedef int  v4i  __attribute__((ext_vector_type(4)));

// R12 = R11 + PAIRED B-frags + DPP xor-8:
//  (1) B-frag cols 8-15 were zero padding (NB=8) and the MFMA outputs for
//      cols 8-15 are discarded anyway (C1 is consumed from cols 0-7 via the
//      xor-8 pack).  So each 64-lane frag now packs TWO k-tiles of the same
//      8 batches: lanes n16<8 = k-tile0, lanes n16>=8 = k-tile1.  One
//      ds_read_b128 of 100%-useful bytes replaces two; B1/B3 operands are
//      reconstructed with DPP row_ror:8 (== xor 8 inside 16-lane rows).
//      LDS reads/wave/step: 4 -> 2 (the per-CU read drain was ~624 cyc).
//  (2) epilogue __shfl_xor(x,8) -> DPP row_ror:8: 4 ds_swizzles/wave/step
//      move off the (serializing) LDS pipe onto the VALU.
// Pair-buf layout (f16x8 per lane): buf 0,1 = hA dbuf (x@k62, 1@k63);
// buf 2,3 = hB dbuf.  Superstep s: rb=(s+1)&1, wb=s&1 (hazards: R9 proof).
// MFMA 16x16x32_f16: A[m=lane&15][k=(lane>>4)*8+j]; B[k=(lane>>4)*8+j][n=lane&15];
// C reg r = C[row=(lane>>4)*4+r][col=lane&15].  M layout: m=4u+g (gate-interleaved).

__device__ __forceinline__ float ror8f(float v) {
    return __builtin_bit_cast(float,
        __builtin_amdgcn_update_dpp(0, __builtin_bit_cast(int, v),
                                    0x128, 0xf, 0xf, false));   // row_ror:8
}
__device__ __forceinline__ f16x8 ror8x(f16x8 v) {
    v4i a = __builtin_bit_cast(v4i, v); v4i r;
    r.x = __builtin_amdgcn_update_dpp(0, a.x, 0x128, 0xf, 0xf, false);
    r.y = __builtin_amdgcn_update_dpp(0, a.y, 0x128, 0xf, 0xf, false);
    r.z = __builtin_amdgcn_update_dpp(0, a.z, 0x128, 0xf, 0xf, false);
    r.w = __builtin_amdgcn_update_dpp(0, a.w, 0x128, 0xf, 0xf, false);
    return __builtin_bit_cast(f16x8, r);
}

__device__ __forceinline__ f16x8 ldA0(const float* __restrict__ Whh0,
                                      const float* __restrict__ Wih0,
                                      const float* __restrict__ bih0,
                                      const float* __restrict__ bhh0,
                                      int m, int kb) {
    const int u = m >> 2, g = m & 3;
    f16x8 v;
    #pragma unroll
    for (int j = 0; j < 8; ++j) {
        const int k = kb + j;
        float f = 0.f;
        if (u < HID) {
            const int rho = g * HID + u;
            if (k < HID)      f = Whh0[rho * HID + k];
            else if (k == 62) f = Wih0[rho];
            else if (k == 63) f = bih0[rho] + bhh0[rho];
        }
        v[j] = (f16)f;
    }
    return v;
}

__device__ __forceinline__ f16x8 ldA1a(const float* __restrict__ Wih1,
                                       const float* __restrict__ bih1,
                                       const float* __restrict__ bhh1,
                                       int m, int kb) {
    const int u = m >> 2, g = m & 3;
    f16x8 v;
    #pragma unroll
    for (int j = 0; j < 8; ++j) {
        const int k = kb + j;
        float f = 0.f;
        if (u < HID) {
            const int rho = g * HID + u;
            if (k < HID)      f = Wih1[rho * HID + k];
            else if (k == 63) f = bih1[rho] + bhh1[rho];
        }
        v[j] = (f16)f;
    }
    return v;
}

__device__ __forceinline__ f16x8 ldA1b(const float* __restrict__ Whh1,
                                       int m, int kb) {
    const int u = m >> 2, g = m & 3;
    f16x8 v;
    #pragma unroll
    for (int j = 0; j < 8; ++j) {
        const int k = kb + j;
        float f = 0.f;
        if (u < HID && k < HID) f = Whh1[(g * HID + u) * HID + k];
        v[j] = (f16)f;
    }
    return v;
}

#define MFMA16(A, B, C) __builtin_amdgcn_mfma_f32_16x16x32_f16((A), (B), (C), 0, 0, 0)

__global__ __launch_bounds__(BLK, 1)
void lstm2_mfma(const float* __restrict__ x,
                const float* __restrict__ Wih0,
                const float* __restrict__ Whh0,
                const float* __restrict__ bih0,
                const float* __restrict__ bhh0,
                const float* __restrict__ Wih1,
                const float* __restrict__ Whh1,
                const float* __restrict__ bih1,
                const float* __restrict__ bhh1,
                const float* __restrict__ Wfc,
                const float* __restrict__ bfc,
                float* __restrict__ out)
{
    __shared__ __align__(16) f16 BPH [4 * 64 * 8];   // 4,096 B: paired B frags (dbuf hA/hB)
    __shared__ f16   xs16[NB][T_SEQ];                // 8,192 B: staged x (f16)
    __shared__ float hfin[HID][NB];                  // 1,600 B: final hB fp32

    const int tid  = threadIdx.x;
    const int w    = tid >> 6;                       // 0..12 = Mtile index (both layers)
    const int lane = tid & 63;
    const int n16  = lane & 15;
    const int quad = lane >> 4;
    const int bb0  = blockIdx.x * NB;

    const float* xg = x + (long)bb0 * T_SEQ;

    // ---- one-time: zero B frags; stage x -> f16 LDS ----
    for (int i = tid; i < 4 * 64 * 8; i += BLK) BPH[i] = (f16)0.f;
    for (int i = tid; i < NB * T_SEQ; i += BLK) {
        const int n = i >> 9, tt = i & (T_SEQ - 1);
        xs16[n][tt] = (f16)xg[n * T_SEQ + tt];
    }

    // ---- one-time: this wave's weights for BOTH layers, Mtile w ----
    const int m   = w * 16 + n16;
    const int kb0 = quad * 8, kb1 = 32 + quad * 8;
    const f16x8 a0 = ldA0(Whh0, Wih0, bih0, bhh0, m, kb0);   // L0: [Whh0|x|b]
    const f16x8 a1 = ldA0(Whh0, Wih0, bih0, bhh0, m, kb1);
    const f16x8 v0 = ldA1a(Wih1, bih1, bhh1, m, kb0);        // L1: hA-side [Wih1|b]
    const f16x8 v1 = ldA1a(Wih1, bih1, bhh1, m, kb1);
    const f16x8 v2 = ldA1b(Whh1, m, kb0);                    // L1: hB-side Whh1
    const f16x8 v3 = ldA1b(Whh1, m, kb1);

    __syncthreads();
    // pair-layout: k-slot u lives at lane pl = ((u&31)>>3)*16 + n + (u>>5)*8,
    // f16 element u&7.  k=62,63 -> pl = 56+n.
    // "1.0" bias (k=63) in both hA bufs; x(0) into hA buf1 (read at s=0)
    if (tid < NB) {
        BPH[(0 * 64 + 56 + tid) * 8 + 7] = (f16)1.f;
        BPH[(1 * 64 + 56 + tid) * 8 + 7] = (f16)1.f;
        BPH[(1 * 64 + 56 + tid) * 8 + 6] = xs16[tid][0];
    }
    __syncthreads();

    // per-lane cell state: cols 0-7 track L0 cell (u_, n16), cols 8-15 track
    // L1 cell (u_, n16-8).  u_ fixed per lane for all steps.
    const int  u_    = w * 4 + quad;
    const bool isl0  = (n16 < 8);
    const bool valid = (u_ < HID);
    // step-invariant h write offset inside a 512-f16 pair buffer
    const int  woff  = (((u_ & 31) >> 3) * 16 + (n16 & 7) + ((u_ >> 5) * 8)) * 8 + (u_ & 7);
    float cs = 0.f;
    const f16x8* BPF = (const f16x8*)BPH;

    #pragma clang loop unroll(disable)
    for (int s = 0; s <= T_SEQ; ++s) {
        const int rb = (s + 1) & 1, wb = s & 1;

        // ONE paired read per layer-input: lanes n<8 carry k-tile0, lanes
        // n>=8 carry k-tile1.  B-operand cols 8-15 are don't-care (their C
        // columns are discarded), so no zero-select is needed.
        const f16x8 rA = BPF[rb * 64 + lane];            // hA(s-1) pair
        const f16x8 rB = BPF[(2 + wb) * 64 + lane];      // hB(s-2) pair
        const f16x8 B0 = rA;
        const f16x8 B1 = ror8x(rA);
        const f16x8 B2 = rB;
        const f16x8 B3 = ror8x(rB);

        v4f C0 = {0.f, 0.f, 0.f, 0.f};   // L0 Mtile w
        v4f C1 = {0.f, 0.f, 0.f, 0.f};   // L1 Mtile w
        C0 = MFMA16(a0, B0, C0);
        C0 = MFMA16(a1, B1, C0);
        C1 = MFMA16(v0, B0, C1);
        C1 = MFMA16(v1, B1, C1);
        C1 = MFMA16(v2, B2, C1);
        C1 = MFMA16(v3, B3, C1);

        // pack: cols 0-7 <- C0 (L0), cols 8-15 <- C1 shifted up by 8 (DPP)
        const float sx = ror8f(C1.x);
        const float sy = ror8f(C1.y);
        const float sz = ror8f(C1.z);
        const float sw = ror8f(C1.w);
        v4f CC;
        CC.x = isl0 ? C0.x : sx;
        CC.y = isl0 ? C0.y : sy;
        CC.z = isl0 ? C0.z : sz;
        CC.w = isl0 ? C0.w : sw;

        // L0 half computes hA(s) (steps 0..T-1); L1 half computes hB(s-1) (steps 1..T)
        const bool active = isl0 ? (s < T_SEQ) : (s >= 1);

        // ---- packed LSTM epilogue, Montgomery batched rcp (7 transcendentals) ----
        const float e1 = __expf(-CC.x);
        const float e2 = __expf(-CC.y);
        const float e3 = __expf(-2.f * CC.z);
        const float e4 = __expf(-CC.w);
        const float d1 = 1.f + e1, d2 = 1.f + e2, d3 = 1.f + e3, d4 = 1.f + e4;
        const float p2 = d1 * d2, p3 = p2 * d3, p4 = p3 * d4;
        const float i4 = __builtin_amdgcn_rcpf(p4);
        const float go = i4 * p3;                 /* 1/d4 */
        const float i3 = i4 * d4;
        const float r3 = i3 * p2;                 /* 1/d3 */
        const float i2 = i3 * d3;
        const float gf = i2 * d1;                 /* 1/d2 */
        const float gi = i2 * d2;                 /* 1/d1 */
        const float gg = fmaf(2.f, r3, -1.f);
        const float csn = fmaf(gf, cs, gi * gg);
        cs = active ? csn : cs;
        const float th = fmaf(2.f, __builtin_amdgcn_rcpf(1.f + __expf(-2.f * cs)), -1.f);
        const float hh = go * th;

        if (valid && active) {
            const int buf = isl0 ? wb : (2 + rb);
            BPH[buf * 512 + woff] = (f16)hh;
            if (!isl0 && s == T_SEQ) hfin[u_][n16 & 7] = hh;
        }

        // x(s+1) -> hA write-buf @k62 (pair lane 56+n); read at s+1
        if (w == 0 && lane < NB && s + 1 < T_SEQ)
            BPH[(wb * 64 + 56 + lane) * 8 + 6] = xs16[lane][s + 1];

        __syncthreads();   // the ONE barrier: publishes hA(s), hB(s-1), x(s+1)
    }

    // ---- classifier: out[n][c] = hB[n] . Wfc[c] + bfc[c] ----
    if (tid < NB * 2) {
        const int nn = tid >> 1, c = tid & 1;
        float acc = bfc[c];
        #pragma unroll
        for (int u = 0; u < HID; ++u)
            acc = fmaf(Wfc[c * HID + u], hfin[u][nn], acc);
        out[(bb0 + nn) * 2 + c] = acc;
    }
}

extern "C" void kernel_launch(void* const* d_in, const int* in_sizes, int n_in,
                              void* d_out, int out_size, void* d_ws, size_t ws_size,
                              hipStream_t stream) {
    const float* x    = (const float*)d_in[0];
    const float* Wih0 = (const float*)d_in[1];
    const float* Whh0 = (const float*)d_in[2];
    const float* bih0 = (const float*)d_in[3];
    const float* bhh0 = (const float*)d_in[4];
    const float* Wih1 = (const float*)d_in[5];
    const float* Whh1 = (const float*)d_in[6];
    const float* bih1 = (const float*)d_in[7];
    const float* bhh1 = (const float*)d_in[8];
    const float* Wfc  = (const float*)d_in[9];
    const float* bfc  = (const float*)d_in[10];
    float* out = (float*)d_out;

    const int B = in_sizes[0] / T_SEQ;   // D == 1
    const int grid = B / NB;             // 2048/8 = 256 blocks -> 1 block/CU

    hipLaunchKernelGGL(lstm2_mfma, dim3(grid), dim3(BLK), 0, stream,
                       x, Wih0, Whh0, bih0, bhh0, Wih1, Whh1, bih1, bhh1,
                       Wfc, bfc, out);
}

// Round 3
// 369.823 us; speedup vs baseline: 1.1844x; 1.1844x over previous
//
#include <hip/hip_runtime.h>

#define T_SEQ 512
#define HID   50
#define NB    8           // batch rows per block (MFMA N=16: cols 0-7 = L0 batch, 8-15 = L1 batch)
#define BLK   832         // 13 waves; wave w owns L0 Mtile w AND L1 Mtile w

typedef float v4f  __attribute__((ext_vector_type(4)));
typedef _Float16 f16;
typedef f16  f16x8 __attribute__((ext_vector_type(8)));

// R13 = R11 (revert R12's paired frags + DPP: they put VALU movs and DPP/MFMA
// hazards on the serial chain -> 342->406us) with DUPLICATE-COLUMN layout:
//  (1) every h is written to LDS TWICE (cols n and n+8, second ds_write_b16
//      with +128B immediate offset, off the critical path).  B-frag cols 8-15
//      then duplicate cols 0-7, so C1 (L1 MFMA) cols 8-15 natively hold the
//      L1 results those lanes consume: the 4 ds_swizzle pack (`shfl_xor 8`,
//      ~120cyc LDS-pipe latency ON the serial chain) becomes a pure
//      reg-to-reg cndmask select.  Reads stay 4 shared b128/wave (R11 form).
//  (2) C1 4-deep dependent MFMA chain -> two independent 2-chains + v_add x4.
//  (3) loop-invariant zero accumulator CZ (kills 8 v_mov C-inits per step).
// LDS tiles (f16, 8 k-tiles of 32): 0,1=hA buf0 (x@k62,1@k63); 2,3=hA buf1;
// 4,5=hB buf0; 6,7=hB buf1. Superstep s: rb=(s+1)&1, wb=s&1 (hazards: R9 proof).
// MFMA 16x16x32_f16: A[m=lane&15][k=(lane>>4)*8+j]; B[k=(lane>>4)*8+j][n=lane&15];
// C reg r = C[row=(lane>>4)*4+r][col=lane&15].  M layout: m=4u+g (gate-interleaved).

__device__ __forceinline__ f16x8 ldA0(const float* __restrict__ Whh0,
                                      const float* __restrict__ Wih0,
                                      const float* __restrict__ bih0,
                                      const float* __restrict__ bhh0,
                                      int m, int kb) {
    const int u = m >> 2, g = m & 3;
    f16x8 v;
    #pragma unroll
    for (int j = 0; j < 8; ++j) {
        const int k = kb + j;
        float f = 0.f;
        if (u < HID) {
            const int rho = g * HID + u;
            if (k < HID)      f = Whh0[rho * HID + k];
            else if (k == 62) f = Wih0[rho];
            else if (k == 63) f = bih0[rho] + bhh0[rho];
        }
        v[j] = (f16)f;
    }
    return v;
}

__device__ __forceinline__ f16x8 ldA1a(const float* __restrict__ Wih1,
                                       const float* __restrict__ bih1,
                                       const float* __restrict__ bhh1,
                                       int m, int kb) {
    const int u = m >> 2, g = m & 3;
    f16x8 v;
    #pragma unroll
    for (int j = 0; j < 8; ++j) {
        const int k = kb + j;
        float f = 0.f;
        if (u < HID) {
            const int rho = g * HID + u;
            if (k < HID)      f = Wih1[rho * HID + k];
            else if (k == 63) f = bih1[rho] + bhh1[rho];
        }
        v[j] = (f16)f;
    }
    return v;
}

__device__ __forceinline__ f16x8 ldA1b(const float* __restrict__ Whh1,
                                       int m, int kb) {
    const int u = m >> 2, g = m & 3;
    f16x8 v;
    #pragma unroll
    for (int j = 0; j < 8; ++j) {
        const int k = kb + j;
        float f = 0.f;
        if (u < HID && k < HID) f = Whh1[(g * HID + u) * HID + k];
        v[j] = (f16)f;
    }
    return v;
}

#define MFMA16(A, B, C) __builtin_amdgcn_mfma_f32_16x16x32_f16((A), (B), (C), 0, 0, 0)

__global__ __launch_bounds__(BLK, 1)
void lstm2_mfma(const float* __restrict__ x,
                const float* __restrict__ Wih0,
                const float* __restrict__ Whh0,
                const float* __restrict__ bih0,
                const float* __restrict__ bhh0,
                const float* __restrict__ Wih1,
                const float* __restrict__ Whh1,
                const float* __restrict__ bih1,
                const float* __restrict__ bhh1,
                const float* __restrict__ Wfc,
                const float* __restrict__ bfc,
                float* __restrict__ out)
{
    __shared__ __align__(16) f16 BPH [8 * 64 * 8];   // 8,192 B: B frags (dbuf hA/hB, dup cols)
    __shared__ f16   xs16[NB][T_SEQ];                // 8,192 B: staged x (f16)
    __shared__ float hfin[HID][NB];                  // 1,600 B: final hB fp32

    const int tid  = threadIdx.x;
    const int w    = tid >> 6;                       // 0..12 = Mtile index (both layers)
    const int lane = tid & 63;
    const int n16  = lane & 15;
    const int quad = lane >> 4;
    const int bb0  = blockIdx.x * NB;

    const float* xg = x + (long)bb0 * T_SEQ;

    // ---- one-time: zero B frags; stage x -> f16 LDS ----
    for (int i = tid; i < 8 * 64 * 8; i += BLK) BPH[i] = (f16)0.f;
    for (int i = tid; i < NB * T_SEQ; i += BLK) {
        const int n = i >> 9, tt = i & (T_SEQ - 1);
        xs16[n][tt] = (f16)xg[n * T_SEQ + tt];
    }

    // ---- one-time: this wave's weights for BOTH layers, Mtile w ----
    const int m   = w * 16 + n16;
    const int kb0 = quad * 8, kb1 = 32 + quad * 8;
    const f16x8 a0 = ldA0(Whh0, Wih0, bih0, bhh0, m, kb0);   // L0: [Whh0|x|b]
    const f16x8 a1 = ldA0(Whh0, Wih0, bih0, bhh0, m, kb1);
    const f16x8 v0 = ldA1a(Wih1, bih1, bhh1, m, kb0);        // L1: hA-side [Wih1|b]
    const f16x8 v1 = ldA1a(Wih1, bih1, bhh1, m, kb1);
    const f16x8 v2 = ldA1b(Whh1, m, kb0);                    // L1: hB-side Whh1
    const f16x8 v3 = ldA1b(Whh1, m, kb1);

    __syncthreads();
    // "1.0" bias (k=63) in both hA bufs, BOTH column halves; x(0) likewise
    if (tid < NB) {
        BPH[(1 * 64 + 48 + tid) * 8 + 7] = (f16)1.f;
        BPH[(1 * 64 + 56 + tid) * 8 + 7] = (f16)1.f;
        BPH[(3 * 64 + 48 + tid) * 8 + 7] = (f16)1.f;
        BPH[(3 * 64 + 56 + tid) * 8 + 7] = (f16)1.f;
        BPH[(3 * 64 + 48 + tid) * 8 + 6] = xs16[tid][0];
        BPH[(3 * 64 + 56 + tid) * 8 + 6] = xs16[tid][0];
    }
    __syncthreads();

    // per-lane cell state: cols 0-7 track L0 cell (u_, n16), cols 8-15 track
    // L1 cell (u_, n16-8).  u_ fixed per lane for all steps.
    const int  u_    = w * 4 + quad;
    const bool isl0  = (n16 < 8);
    const bool valid = (u_ < HID);
    // step-invariant part of the h write index (f16 elements); tile adds tb*512.
    // Written twice: +0 (col n) and +64 f16 (col n+8).
    const int  wbase = (((u_ & 31) >> 3) * 16 + (n16 & 7)) * 8 + (u_ & 7) + (u_ >> 5) * 512;
    float cs = 0.f;
    const f16x8* BPF = (const f16x8*)BPH;
    const v4f CZ = {0.f, 0.f, 0.f, 0.f};            // loop-invariant zero accumulator

    #pragma clang loop unroll(disable)
    for (int s = 0; s <= T_SEQ; ++s) {
        const int rb = (s + 1) & 1, wb = s & 1;

        // shared hA(s-1) frags feed BOTH layers; hB(s-2) frags feed L1 only
        const f16x8 B0 = BPF[(2 * rb + 0) * 64 + lane];
        const f16x8 B1 = BPF[(2 * rb + 1) * 64 + lane];
        const f16x8 B2 = BPF[(4 + 2 * wb + 0) * 64 + lane];
        const f16x8 B3 = BPF[(4 + 2 * wb + 1) * 64 + lane];

        v4f C0 = MFMA16(a0, B0, CZ);     // L0 Mtile w (valid in ALL 16 cols: dup)
        C0 = MFMA16(a1, B1, C0);
        v4f C1h = MFMA16(v0, B0, CZ);    // L1, hA side
        C1h = MFMA16(v1, B1, C1h);
        v4f C1r = MFMA16(v2, B2, CZ);    // L1, hB side (independent 2-chain)
        C1r = MFMA16(v3, B3, C1r);

        // select: cols 0-7 <- C0 (L0), cols 8-15 <- C1h+C1r (L1). reg-to-reg.
        v4f CC;
        CC.x = isl0 ? C0.x : (C1h.x + C1r.x);
        CC.y = isl0 ? C0.y : (C1h.y + C1r.y);
        CC.z = isl0 ? C0.z : (C1h.z + C1r.z);
        CC.w = isl0 ? C0.w : (C1h.w + C1r.w);

        // L0 half computes hA(s) (steps 0..T-1); L1 half computes hB(s-1) (steps 1..T)
        const bool active = isl0 ? (s < T_SEQ) : (s >= 1);

        // ---- packed LSTM epilogue, Montgomery batched rcp (7 transcendentals) ----
        const float e1 = __expf(-CC.x);
        const float e2 = __expf(-CC.y);
        const float e3 = __expf(-2.f * CC.z);
        const float e4 = __expf(-CC.w);
        const float d1 = 1.f + e1, d2 = 1.f + e2, d3 = 1.f + e3, d4 = 1.f + e4;
        const float p2 = d1 * d2, p3 = p2 * d3, p4 = p3 * d4;
        const float i4 = __builtin_amdgcn_rcpf(p4);
        const float go = i4 * p3;                 /* 1/d4 */
        const float i3 = i4 * d4;
        const float r3 = i3 * p2;                 /* 1/d3 */
        const float i2 = i3 * d3;
        const float gf = i2 * d1;                 /* 1/d2 */
        const float gi = i2 * d2;                 /* 1/d1 */
        const float gg = fmaf(2.f, r3, -1.f);
        const float csn = fmaf(gf, cs, gi * gg);
        cs = active ? csn : cs;
        const float th = fmaf(2.f, __builtin_amdgcn_rcpf(1.f + __expf(-2.f * cs)), -1.f);
        const float hh = go * th;

        if (valid && active) {
            const int tb = isl0 ? (2 * wb) : (4 + 2 * rb);
            f16* p = &BPH[tb * 512 + wbase];
            p[0]  = (f16)hh;              // col n
            p[64] = (f16)hh;              // col n+8 (duplicate half)
            if (!isl0 && s == T_SEQ) hfin[u_][n16 & 7] = hh;
        }

        // x(s+1) -> hA write-buf @k62, both column halves; read at s+1
        if (w == 0 && lane < NB && s + 1 < T_SEQ) {
            const f16 xv = xs16[lane][s + 1];
            BPH[((2 * wb + 1) * 64 + 48 + lane) * 8 + 6] = xv;
            BPH[((2 * wb + 1) * 64 + 56 + lane) * 8 + 6] = xv;
        }

        __syncthreads();   // the ONE barrier: publishes hA(s), hB(s-1), x(s+1)
    }

    // ---- classifier: out[n][c] = hB[n] . Wfc[c] + bfc[c] ----
    if (tid < NB * 2) {
        const int nn = tid >> 1, c = tid & 1;
        float acc = bfc[c];
        #pragma unroll
        for (int u = 0; u < HID; ++u)
            acc = fmaf(Wfc[c * HID + u], hfin[u][nn], acc);
        out[(bb0 + nn) * 2 + c] = acc;
    }
}

extern "C" void kernel_launch(void* const* d_in, const int* in_sizes, int n_in,
                              void* d_out, int out_size, void* d_ws, size_t ws_size,
                              hipStream_t stream) {
    const float* x    = (const float*)d_in[0];
    const float* Wih0 = (const float*)d_in[1];
    const float* Whh0 = (const float*)d_in[2];
    const float* bih0 = (const float*)d_in[3];
    const float* bhh0 = (const float*)d_in[4];
    const float* Wih1 = (const float*)d_in[5];
    const float* Whh1 = (const float*)d_in[6];
    const float* bih1 = (const float*)d_in[7];
    const float* bhh1 = (const float*)d_in[8];
    const float* Wfc  = (const float*)d_in[9];
    const float* bfc  = (const float*)d_in[10];
    float* out = (float*)d_out;

    const int B = in_sizes[0] / T_SEQ;   // D == 1
    const int grid = B / NB;             // 2048/8 = 256 blocks -> 1 block/CU

    hipLaunchKernelGGL(lstm2_mfma, dim3(grid), dim3(BLK), 0, stream,
                       x, Wih0, Whh0, bih0, bhh0, Wih1, Whh1, bih1, bhh1,
                       Wfc, bfc, out);
}